// Round 3
// baseline (318.490 us; speedup 1.0000x reference)
//
#include <hip/hip_runtime.h>

typedef __attribute__((ext_vector_type(8))) short bf16x8;
typedef __attribute__((ext_vector_type(4))) float f32x4;

static __device__ __forceinline__ unsigned short f32_to_bf16(float f) {
    unsigned int x = __float_as_uint(f);
    x += 0x7fffu + ((x >> 16) & 1u);   // round-to-nearest-even
    return (unsigned short)(x >> 16);
}

// Banded GEMM cost volume: out[n,j,h,x] = G[y=x-j, x], G = R̂ᵀ·L̂ (per n,h).
// One block = (n, h, x-tile TX). MFMA 16x16x32 bf16.
// Shared pool layout per level: [ uni (fp32 stage / obuf) | Abf | Bbf ].
template<int C, int H, int W, int D, int TX, int NT>
__device__ __forceinline__ void level_body(char* pool, int bx,
    const float* __restrict__ Lp, const float* __restrict__ Rp,
    float* __restrict__ out)
{
    constexpr int RS = TX + D;        // staged y range: [X0-D, X0+TX)
    constexpr int AS = C + 8;         // bf16 row stride (halfwords)
    constexpr int KC = C / 32;        // mfma k-steps
    constexpr int NSTRIP = TX / 16;   // x-strips per block
    constexpr int NSUB = (NT / 64) / NSTRIP;  // waves sharing a strip (split y-tiles)
    constexpr int OST = TX + 4;       // obuf stride: quad scatter -> 2-way (free)
    constexpr int STAGE_F = C * (TX + RS);
    constexpr int OBUF_F  = D * OST;
    constexpr int UNI_F   = STAGE_F > OBUF_F ? STAGE_F : OBUF_F;
    static_assert((RS * AS * 2) % 16 == 0, "Bbf alignment");

    float* uni = (float*)pool;
    unsigned short* Abf = (unsigned short*)(pool + ((UNI_F * 4 + 15) & ~15));
    unsigned short* Bbf = Abf + RS * AS;
    float* lsf  = uni;             // [c][x], C x TX
    float* rsf  = uni + C * TX;    // [c][y], C x RS
    float* obuf = uni;             // [j][x], D x OST (after norm)

    const int tid = threadIdx.x;
    constexpr int NXB = W / TX;
    const int xb = bx % NXB;
    const int h  = (bx / NXB) % H;
    const int n  = bx / (NXB * H);
    const int X0 = xb * TX;

    // ---- stage L tile (coalesced float4) ----
    for (int i = tid; i < C * TX / 4; i += NT) {
        const int c = i / (TX / 4), v = i % (TX / 4);
        *(float4*)&lsf[c * TX + 4 * v] =
            *(const float4*)&Lp[(((size_t)n * C + c) * H + h) * W + X0 + 4 * v];
    }
    // ---- stage R tile, y in [X0-D, X0+TX), zero-fill y<0 ----
    for (int i = tid; i < C * RS / 4; i += NT) {
        const int c = i / (RS / 4), v = i % (RS / 4);
        const int y = X0 - D + 4 * v;
        const float* src = &Rp[(((size_t)n * C + c) * H + h) * W];
        float4 val;
        if (y >= 0) val = *(const float4*)&src[y];
        else {
            val.x = (y + 0) >= 0 ? src[y + 0] : 0.f;
            val.y = (y + 1) >= 0 ? src[y + 1] : 0.f;
            val.z = (y + 2) >= 0 ? src[y + 2] : 0.f;
            val.w = (y + 3) >= 0 ? src[y + 3] : 0.f;
        }
        *(float4*)&rsf[c * RS + 4 * v] = val;
    }
    __syncthreads();

    // ---- two-pass L2 norm per column (no register arrays -> no spills),
    //      emit bf16 transposed [spatial][c], padded stride AS ----
    for (int col = tid; col < TX + RS; col += NT) {
        const float* src; int stride; unsigned short* dst;
        if (col < TX) { src = lsf + col;        stride = TX; dst = Bbf + col * AS; }
        else          { src = rsf + (col - TX); stride = RS; dst = Abf + (col - TX) * AS; }
        float s = 0.f;
        #pragma unroll 8
        for (int c = 0; c < C; ++c) { const float v = src[c * stride]; s += v * v; }
        const float inv = 1.0f / fmaxf(sqrtf(s), 1e-12f);
        #pragma unroll
        for (int c0 = 0; c0 < C; c0 += 8) {
            union { unsigned short us[8]; uint4 q; } p;
            #pragma unroll
            for (int k = 0; k < 8; ++k)
                p.us[k] = f32_to_bf16(src[(c0 + k) * stride] * inv);
            *(uint4*)&dst[c0] = p.q;
        }
    }
    __syncthreads();

    // ---- banded MFMA sweep ----
    const int wave = tid >> 6, lane = tid & 63;
    const int strip = wave % NSTRIP;      // x-strip [16*strip, 16*strip+16)
    const int sub   = wave / NSTRIP;      // y-tile subset
    const int colc = lane & 15, quad = lane >> 4;

    bf16x8 bfr[KC];
    #pragma unroll
    for (int kc = 0; kc < KC; ++kc)
        bfr[kc] = *(const bf16x8*)&Bbf[(strip * 16 + colc) * AS + kc * 32 + quad * 8];

    const int xl = strip * 16 + colc;
    #pragma unroll
    for (int t = sub; t <= D / 16; t += NSUB) {
        const int yt = strip + t;
        f32x4 acc = {0.f, 0.f, 0.f, 0.f};
        #pragma unroll
        for (int kc = 0; kc < KC; ++kc) {
            const bf16x8 a =
                *(const bf16x8*)&Abf[(yt * 16 + colc) * AS + kc * 32 + quad * 8];
            acc = __builtin_amdgcn_mfma_f32_16x16x32_bf16(a, bfr[kc], acc, 0, 0, 0);
        }
        // D layout: col = lane&15 (x), row = quad*4 + r (y); j = x - y
        const int jb = D + xl - yt * 16 - quad * 4;
        #pragma unroll
        for (int r = 0; r < 4; ++r) {
            const int j = jb - r;
            if (j >= 0 && j < D) obuf[j * OST + xl] = acc[r];
        }
    }
    __syncthreads();

    // ---- coalesced float4 writeout of the band ----
    constexpr int JV = TX / 4;
    for (int i = tid; i < D * TX / 4; i += NT) {
        const int j = i / JV, c4 = i % JV;
        *(float4*)&out[(((size_t)n * D + j) * H + h) * W + X0 + 4 * c4] =
            *(const float4*)&obuf[j * OST + 4 * c4];
    }
}

// Pool: max over levels.
//  L0 <32,256,512,128,64>: uni 34816 + Abf 15360 + Bbf 5120 = 55296 B
//  L1 <64,128,256, 64,32>: uni 32768 + Abf 13824 + Bbf 4608 = 51200 B
//  L2 <96, 64,128, 32,32>: uni 36864 + Abf 13312 + Bbf 6656 = 56832 B
#define POOL_BYTES 56832

__global__ __launch_bounds__(256)
void cost_volume_all(const float* __restrict__ l0, const float* __restrict__ r0,
                     const float* __restrict__ l1, const float* __restrict__ r1,
                     const float* __restrict__ l2, const float* __restrict__ r2,
                     float* __restrict__ o0, float* __restrict__ o1,
                     float* __restrict__ o2)
{
    __shared__ __align__(16) char pool[POOL_BYTES];
    const int bx = blockIdx.x;
    if (bx < 4096) {                     // L0: 2*256*(512/64)
        level_body<32, 256, 512, 128, 64, 256>(pool, bx, l0, r0, o0);
    } else if (bx < 4096 + 2048) {       // L1: 2*128*(256/32)
        level_body<64, 128, 256, 64, 32, 256>(pool, bx - 4096, l1, r1, o1);
    } else {                             // L2: 2*64*(128/32)
        level_body<96, 64, 128, 32, 32, 256>(pool, bx - 6144, l2, r2, o2);
    }
}

extern "C" void kernel_launch(void* const* d_in, const int* in_sizes, int n_in,
                              void* d_out, int out_size, void* d_ws, size_t ws_size,
                              hipStream_t stream) {
    (void)in_sizes; (void)n_in; (void)d_ws; (void)ws_size; (void)out_size;
    const float* l0 = (const float*)d_in[0];
    const float* r0 = (const float*)d_in[1];
    const float* l1 = (const float*)d_in[2];
    const float* r1 = (const float*)d_in[3];
    const float* l2 = (const float*)d_in[4];
    const float* r2 = (const float*)d_in[5];
    // max_disparity = 128 fixed by harness shapes: D = 128, 64, 32.

    float* o0 = (float*)d_out;
    float* o1 = o0 + (size_t)2 * 128 * 256 * 512;
    float* o2 = o1 + (size_t)2 * 64 * 128 * 256;

    cost_volume_all<<<4096 + 2048 + 512, 256, 0, stream>>>(
        l0, r0, l1, r1, l2, r2, o0, o1, o2);
}